// Round 1
// baseline (140.652 us; speedup 1.0000x reference)
//
#include <hip/hip_runtime.h>
#include <hip/hip_bf16.h>

typedef __attribute__((ext_vector_type(8))) short bf16x8;
typedef __attribute__((ext_vector_type(4))) float f32x4;
using bf16 = __hip_bfloat16;

static constexpr int Mdim = 512;   // A batch
static constexpr int Ndim = 64;    // B batch
static constexpr int Cdim = 128;   // channels (K of the GEMM)
static constexpr int Pdim = 64;    // H*W positions
static constexpr float EPS_ADD = 0.001f;

// ---------------------------------------------------------------------------
// prep_A: A[M][C][P] f32  ->  Abf[(m*64+p)][c] bf16   (transpose C<->P + cast)
// One block per m. LDS tile padded to stride 65 to kill bank conflicts.
// ---------------------------------------------------------------------------
__global__ void prep_A_kernel(const float* __restrict__ A, bf16* __restrict__ Abf) {
    __shared__ float lds[128 * 65];
    const int m = blockIdx.x;
    const int t = threadIdx.x;
    const float* __restrict__ Am = A + (size_t)m * (Cdim * Pdim);

    // load 8192 floats coalesced as float4; lds[c*65 + p]
#pragma unroll
    for (int i = 0; i < 8; ++i) {
        int v = t + i * 256;          // 0..2047 float4 index
        int gidx = v * 4;
        int c = gidx >> 6, p = gidx & 63;   // 4 consecutive p, same c
        float4 val = *reinterpret_cast<const float4*>(Am + gidx);
        float* dst = &lds[c * 65 + p];
        dst[0] = val.x; dst[1] = val.y; dst[2] = val.z; dst[3] = val.w;
    }
    __syncthreads();

    // write bf16 pairs: out row p (length 128 in c), coalesced 4B stores
    bf16* __restrict__ dstm = Abf + (size_t)m * (Pdim * Cdim);
#pragma unroll
    for (int i = 0; i < 16; ++i) {
        int pr = t + i * 256;         // 0..4095 pair index
        int p = pr >> 6;
        int c = (pr & 63) << 1;
        float f0 = lds[c * 65 + p];
        float f1 = lds[(c + 1) * 65 + p];
        union { bf16 h[2]; unsigned u; } pk;
        pk.h[0] = __float2bfloat16(f0);
        pk.h[1] = __float2bfloat16(f1);
        *reinterpret_cast<unsigned*>(dstm + p * Cdim + c) = pk.u;
    }
}

// ---------------------------------------------------------------------------
// prep_G: Gbf[(n*64+q)][d] = bf16( sum_c B[n][c][q] * Wg[c][d] )
// Grid 256: block = (n, 16-q slab). B[n] staged in LDS; Wg streamed (L2-hot).
// ---------------------------------------------------------------------------
__global__ void prep_G_kernel(const float* __restrict__ B, const float* __restrict__ Wg,
                              bf16* __restrict__ Gbf) {
    __shared__ float ldsB[128 * 65];
    const int n  = blockIdx.x >> 2;
    const int q0 = (blockIdx.x & 3) * 16;
    const int t = threadIdx.x;
    const float* __restrict__ Bn = B + (size_t)n * (Cdim * Pdim);

#pragma unroll
    for (int i = 0; i < 8; ++i) {
        int v = t + i * 256;
        int gidx = v * 4;
        int c = gidx >> 6, q = gidx & 63;
        float4 val = *reinterpret_cast<const float4*>(Bn + gidx);
        float* dst = &ldsB[c * 65 + q];
        dst[0] = val.x; dst[1] = val.y; dst[2] = val.z; dst[3] = val.w;
    }
    __syncthreads();

    const int d  = t & 127;
    const int qb = q0 + (t >> 7) * 8;   // 8 q's per thread
    float acc[8] = {0.f, 0.f, 0.f, 0.f, 0.f, 0.f, 0.f, 0.f};
    for (int c = 0; c < 128; ++c) {
        float w = Wg[c * 128 + d];      // coalesced, L2-resident
#pragma unroll
        for (int qi = 0; qi < 8; ++qi)
            acc[qi] = fmaf(ldsB[c * 65 + qb + qi], w, acc[qi]);  // LDS broadcast
    }
#pragma unroll
    for (int qi = 0; qi < 8; ++qi)
        Gbf[(size_t)(n * 64 + qb + qi) * Cdim + d] = __float2bfloat16(acc[qi]);
}

// ---------------------------------------------------------------------------
// gemm_max: one wave per (m, n). 64x64 tile = 4x4 of 16x16x32 bf16 MFMA,
// K=128 fully unrolled. Epilogue: max over q (columns) -> relu + eps ->
// out[m*4096 + n*64 + p].
// Fragment layout (verified m92 pattern): A and G both [row][K] bf16;
// lane&15 -> row, (lane>>4)*8 -> k-octet; C/D: col=lane&15, row=(lane>>4)*4+reg.
// ---------------------------------------------------------------------------
__global__ void gemm_max_kernel(const bf16* __restrict__ Abf, const bf16* __restrict__ Gbf,
                                float* __restrict__ out) {
    const int wid  = blockIdx.x * 4 + (threadIdx.x >> 6);
    const int lane = threadIdx.x & 63;
    const int m = wid >> 6;
    const int n = wid & 63;
    const int r = lane & 15;
    const int g = lane >> 4;

    const bf16* __restrict__ Arow = Abf + (size_t)m * 64 * 128;
    const bf16* __restrict__ Grow = Gbf + (size_t)n * 64 * 128;

    f32x4 acc[4][4];
#pragma unroll
    for (int rt = 0; rt < 4; ++rt)
#pragma unroll
        for (int ct = 0; ct < 4; ++ct)
            acc[rt][ct] = (f32x4){0.f, 0.f, 0.f, 0.f};

#pragma unroll
    for (int kk = 0; kk < 4; ++kk) {
        const int ko = kk * 32 + g * 8;
        bf16x8 a[4], b[4];
#pragma unroll
        for (int rt = 0; rt < 4; ++rt)
            a[rt] = *reinterpret_cast<const bf16x8*>(Arow + (rt * 16 + r) * 128 + ko);
#pragma unroll
        for (int ct = 0; ct < 4; ++ct)
            b[ct] = *reinterpret_cast<const bf16x8*>(Grow + (ct * 16 + r) * 128 + ko);
#pragma unroll
        for (int rt = 0; rt < 4; ++rt)
#pragma unroll
            for (int ct = 0; ct < 4; ++ct)
                acc[rt][ct] = __builtin_amdgcn_mfma_f32_16x16x32_bf16(a[rt], b[ct], acc[rt][ct], 0, 0, 0);
    }

    // epilogue: per row, max over the 64 columns (= all q of this n)
    float* __restrict__ obase = out + (size_t)m * 4096 + n * 64;
#pragma unroll
    for (int rt = 0; rt < 4; ++rt) {
        float v[4];
#pragma unroll
        for (int j = 0; j < 4; ++j)
            v[j] = fmaxf(fmaxf(acc[rt][0][j], acc[rt][1][j]),
                         fmaxf(acc[rt][2][j], acc[rt][3][j]));
        // butterfly max across the 16 lanes of this group (cols)
#pragma unroll
        for (int off = 8; off >= 1; off >>= 1) {
#pragma unroll
            for (int j = 0; j < 4; ++j)
                v[j] = fmaxf(v[j], __shfl_xor(v[j], off));
        }
        if (r == 0) {
            int p = rt * 16 + g * 4;   // rows this lane-group owns
            float4 o;
            o.x = fmaxf(v[0], 0.f) + EPS_ADD;
            o.y = fmaxf(v[1], 0.f) + EPS_ADD;
            o.z = fmaxf(v[2], 0.f) + EPS_ADD;
            o.w = fmaxf(v[3], 0.f) + EPS_ADD;
            *reinterpret_cast<float4*>(obase + p) = o;
        }
    }
}

// ---------------------------------------------------------------------------
extern "C" void kernel_launch(void* const* d_in, const int* in_sizes, int n_in,
                              void* d_out, int out_size, void* d_ws, size_t ws_size,
                              hipStream_t stream) {
    const float* A  = (const float*)d_in[0];
    const float* B  = (const float*)d_in[1];
    const float* Wg = (const float*)d_in[2];
    float* out = (float*)d_out;

    bf16* Abf = (bf16*)d_ws;                                        // 32768 x 128 bf16 = 8 MiB
    bf16* Gbf = (bf16*)((char*)d_ws + (size_t)Mdim * Pdim * Cdim * sizeof(bf16)); // 4096 x 128 bf16 = 1 MiB

    prep_A_kernel<<<Mdim, 256, 0, stream>>>(A, Abf);
    prep_G_kernel<<<256, 256, 0, stream>>>(B, Wg, Gbf);
    gemm_max_kernel<<<(Mdim * Ndim) / 4, 256, 0, stream>>>(Abf, Gbf, out);
}

// Round 4
// 83.497 us; speedup vs baseline: 1.6845x; 1.6845x over previous
//
#include <hip/hip_runtime.h>
#include <hip/hip_bf16.h>
#include <stdint.h>

typedef __attribute__((ext_vector_type(8))) short bf16x8;
typedef __attribute__((ext_vector_type(4))) float f32x4;
using bf16 = __hip_bfloat16;

static constexpr int Mdim = 512;   // A batch
static constexpr int Ndim = 64;    // B batch
static constexpr int Cdim = 128;   // channels (K of the GEMM)
static constexpr int Pdim = 64;    // H*W positions
static constexpr float EPS_ADD = 0.001f;

// ---------------------------------------------------------------------------
// async global->LDS, 16B per lane
// ---------------------------------------------------------------------------
__device__ __forceinline__ void gll16(const void* gsrc, void* ldst) {
    const __attribute__((address_space(1))) unsigned int* g =
        (const __attribute__((address_space(1))) unsigned int*)gsrc;
    __attribute__((address_space(3))) unsigned int* l =
        (__attribute__((address_space(3))) unsigned int*)(uintptr_t)ldst;
    __builtin_amdgcn_global_load_lds(g, l, 16, 0, 0);
}

// ---------------------------------------------------------------------------
// prep_A: A[M][C][P] f32  ->  Abf[(m*64+p)][c] bf16   (transpose C<->P + cast)
// ---------------------------------------------------------------------------
__global__ void prep_A_kernel(const float* __restrict__ A, bf16* __restrict__ Abf) {
    __shared__ float lds[128 * 65];
    const int m = blockIdx.x;
    const int t = threadIdx.x;
    const float* __restrict__ Am = A + (size_t)m * (Cdim * Pdim);

#pragma unroll
    for (int i = 0; i < 8; ++i) {
        int v = t + i * 256;
        int gidx = v * 4;
        int c = gidx >> 6, p = gidx & 63;
        float4 val = *reinterpret_cast<const float4*>(Am + gidx);
        float* dst = &lds[c * 65 + p];
        dst[0] = val.x; dst[1] = val.y; dst[2] = val.z; dst[3] = val.w;
    }
    __syncthreads();

    bf16* __restrict__ dstm = Abf + (size_t)m * (Pdim * Cdim);
#pragma unroll
    for (int i = 0; i < 16; ++i) {
        int pr = t + i * 256;
        int p = pr >> 6;
        int c = (pr & 63) << 1;
        float f0 = lds[c * 65 + p];
        float f1 = lds[(c + 1) * 65 + p];
        union { bf16 h[2]; unsigned u; } pk;
        pk.h[0] = __float2bfloat16(f0);
        pk.h[1] = __float2bfloat16(f1);
        *reinterpret_cast<unsigned*>(dstm + p * Cdim + c) = pk.u;
    }
}

// ---------------------------------------------------------------------------
// prep_G: Gbf[(n*64+q)][d] = bf16( sum_c B[n][c][q] * Wg[c][d] )
// ---------------------------------------------------------------------------
__global__ void prep_G_kernel(const float* __restrict__ B, const float* __restrict__ Wg,
                              bf16* __restrict__ Gbf) {
    __shared__ float ldsB[128 * 65];
    const int n  = blockIdx.x >> 2;
    const int q0 = (blockIdx.x & 3) * 16;
    const int t = threadIdx.x;
    const float* __restrict__ Bn = B + (size_t)n * (Cdim * Pdim);

#pragma unroll
    for (int i = 0; i < 8; ++i) {
        int v = t + i * 256;
        int gidx = v * 4;
        int c = gidx >> 6, q = gidx & 63;
        float4 val = *reinterpret_cast<const float4*>(Bn + gidx);
        float* dst = &ldsB[c * 65 + q];
        dst[0] = val.x; dst[1] = val.y; dst[2] = val.z; dst[3] = val.w;
    }
    __syncthreads();

    const int d  = t & 127;
    const int qb = q0 + (t >> 7) * 8;
    float acc[8] = {0.f, 0.f, 0.f, 0.f, 0.f, 0.f, 0.f, 0.f};
    for (int c = 0; c < 128; ++c) {
        float w = Wg[c * 128 + d];
#pragma unroll
        for (int qi = 0; qi < 8; ++qi)
            acc[qi] = fmaf(ldsB[c * 65 + qb + qi], w, acc[qi]);
    }
#pragma unroll
    for (int qi = 0; qi < 8; ++qi)
        Gbf[(size_t)(n * 64 + qb + qi) * Cdim + d] = __float2bfloat16(acc[qi]);
}

// ---------------------------------------------------------------------------
// gemm_max v2b: identical structure to v2; grid bug fixed (2048 blocks) +
// bijective XCD swizzle so the 32 bn-blocks sharing a bmg (A reuse) stay on
// one XCD's L2.
// block = 128 cols (2 n's) x 4 bm-tiles of 128 rows.
//  - G fragments in registers for the whole block (loaded once).
//  - A staged via global_load_lds (16B) into XOR-swizzled LDS, two K-halves
//    double-buffered with counted vmcnt (raw s_barrier; no __syncthreads).
//  - wave = 64x64 output tile; epilogue: max over 64 cols -> relu+eps.
// LDS: 2 x 128 x 64 bf16 = 32 KB.
// ---------------------------------------------------------------------------
__global__ __launch_bounds__(256, 2)
void gemm_max_kernel(const bf16* __restrict__ Abf, const bf16* __restrict__ Gbf,
                     float* __restrict__ out) {
    __shared__ bf16 sA[2][128 * 64];   // [buf][row*64 + k], swizzled
    const int tid  = threadIdx.x;
    const int lane = tid & 63;
    const int w    = tid >> 6;
    const int wr = w >> 1, wc = w & 1;
    const int rr = lane & 15, g = lane >> 4;

    // bijective XCD swizzle: 2048 blocks % 8 XCDs == 0 -> contiguous 256-chunk
    // per XCD; consecutive orig ids (same bmg, bn=0..31) share A row-group.
    const int wg  = (blockIdx.x & 7) * 256 + (blockIdx.x >> 3);
    const int bn  = wg & 31;   // 32 col-tiles of 128
    const int bmg = wg >> 5;   // 64 row-groups of 4x128 rows

    // ---- G fragments resident in registers: bfr[ct][ks] ----
    bf16x8 bfr[4][4];
    {
        const bf16* Gp = Gbf + ((size_t)(bn * 128 + wc * 64 + rr)) * 128 + g * 8;
#pragma unroll
        for (int ct = 0; ct < 4; ++ct)
#pragma unroll
            for (int ks = 0; ks < 4; ++ks)
                bfr[ct][ks] = *reinterpret_cast<const bf16x8*>(Gp + ct * 16 * 128 + ks * 32);
    }

    const char* Abase = (const char*)(Abf + (size_t)bmg * 4 * 128 * 128);

    // stage A-half h (cols h*64..h*64+63) of bm-tile it into sA[buf].
    // LDS row stride 128B; within-row byte b holds global byte b^((row&7)<<4).
    auto stage = [&](int it, int h, int buf) {
#pragma unroll
        for (int j = 0; j < 4; ++j) {
            int f = (j * 256 + tid) * 16;                 // flat LDS byte, 16 KB
            int row = f >> 7;
            int inner = (f & 127) ^ ((row & 7) << 4);     // inverse swizzle on source
            const char* src = Abase + (size_t)it * 32768 + row * 256 + h * 128 + inner;
            gll16(src, (char*)&sA[buf][0] + f);
        }
    };

    f32x4 acc[4][4];
#pragma unroll
    for (int rt = 0; rt < 4; ++rt)
#pragma unroll
        for (int ct = 0; ct < 4; ++ct)
            acc[rt][ct] = (f32x4){0.f, 0.f, 0.f, 0.f};

    auto compute_half = [&](int buf, int ksbase) {
#pragma unroll
        for (int kk = 0; kk < 2; ++kk) {
            const int kb = (kk * 64 + g * 16) ^ ((rr & 7) << 4);  // swizzled k-chunk
            bf16x8 a[4];
#pragma unroll
            for (int rt = 0; rt < 4; ++rt) {
                int row = wr * 64 + rt * 16 + rr;
                a[rt] = *reinterpret_cast<const bf16x8*>((const char*)&sA[buf][0] + row * 128 + kb);
            }
#pragma unroll
            for (int rt = 0; rt < 4; ++rt)
#pragma unroll
                for (int ct = 0; ct < 4; ++ct)
                    acc[rt][ct] = __builtin_amdgcn_mfma_f32_16x16x32_bf16(
                        a[rt], bfr[ct][ksbase + kk], acc[rt][ct], 0, 0, 0);
        }
    };

    // ---- prologue ----
    stage(0, 0, 0);
    stage(0, 1, 1);
    asm volatile("s_waitcnt vmcnt(0)" ::: "memory");
    __builtin_amdgcn_s_barrier();
    __builtin_amdgcn_sched_barrier(0);

#pragma unroll
    for (int it = 0; it < 4; ++it) {
        // K-half 0 (ks 0,1) from buf0
        compute_half(0, 0);
        __builtin_amdgcn_sched_barrier(0);
        // join: drain prev-iter's buf1 writes (and stores); buf0 reads done.
        asm volatile("s_waitcnt vmcnt(0)" ::: "memory");
        __builtin_amdgcn_s_barrier();
        __builtin_amdgcn_sched_barrier(0);
        if (it < 3) stage(it + 1, 0, 0);      // prefetch next h0 under K1 compute

        // K-half 1 (ks 2,3) from buf1
        compute_half(1, 2);
        __builtin_amdgcn_sched_barrier(0);
        __builtin_amdgcn_s_barrier();          // everyone done reading buf1
        __builtin_amdgcn_sched_barrier(0);
        if (it < 3) stage(it + 1, 1, 1);      // prefetch next h1 under epilogue

        // ---- epilogue: max over cols -> relu+eps -> store ----
        {
            const int m = (bmg * 4 + it) * 2 + wr;
            const int n = bn * 2 + wc;
            float* obase = out + (size_t)m * 4096 + n * 64;
#pragma unroll
            for (int rt = 0; rt < 4; ++rt) {
                float v[4];
#pragma unroll
                for (int j = 0; j < 4; ++j)
                    v[j] = fmaxf(fmaxf(acc[rt][0][j], acc[rt][1][j]),
                                 fmaxf(acc[rt][2][j], acc[rt][3][j]));
#pragma unroll
                for (int off = 8; off >= 1; off >>= 1)
#pragma unroll
                    for (int j = 0; j < 4; ++j)
                        v[j] = fmaxf(v[j], __shfl_xor(v[j], off));
                if (rr == 0) {
                    float4 o;
                    o.x = fmaxf(v[0], 0.f) + EPS_ADD;
                    o.y = fmaxf(v[1], 0.f) + EPS_ADD;
                    o.z = fmaxf(v[2], 0.f) + EPS_ADD;
                    o.w = fmaxf(v[3], 0.f) + EPS_ADD;
                    *reinterpret_cast<float4*>(obase + rt * 16 + g * 4) = o;
                }
#pragma unroll
                for (int ct = 0; ct < 4; ++ct)
                    acc[rt][ct] = (f32x4){0.f, 0.f, 0.f, 0.f};
            }
        }

        if (it < 3) {
            // next K-half 0 needs this iter's buf0 prefetch landed:
            // non-store lanes 8 outstanding -> wait oldest 4 (buf0);
            // store lanes 12 -> wait oldest 8 (buf0+buf1). Both safe.
            asm volatile("s_waitcnt vmcnt(4)" ::: "memory");
            __builtin_amdgcn_s_barrier();
            __builtin_amdgcn_sched_barrier(0);
        }
    }
}

// ---------------------------------------------------------------------------
extern "C" void kernel_launch(void* const* d_in, const int* in_sizes, int n_in,
                              void* d_out, int out_size, void* d_ws, size_t ws_size,
                              hipStream_t stream) {
    const float* A  = (const float*)d_in[0];
    const float* B  = (const float*)d_in[1];
    const float* Wg = (const float*)d_in[2];
    float* out = (float*)d_out;

    bf16* Abf = (bf16*)d_ws;                                        // 32768 x 128 bf16 = 8 MiB
    bf16* Gbf = (bf16*)((char*)d_ws + (size_t)Mdim * Pdim * Cdim * sizeof(bf16)); // 4096 x 128 bf16

    prep_A_kernel<<<Mdim, 256, 0, stream>>>(A, Abf);
    prep_G_kernel<<<256, 256, 0, stream>>>(B, Wg, Gbf);

    // rows = M*P = 32768 -> 64 groups of 512; cols = N*P = 4096 -> 32 tiles of 128
    constexpr int GEMM_GRID = (Mdim * Pdim / 512) * (Ndim * Pdim / 128);  // 2048
    gemm_max_kernel<<<GEMM_GRID, 256, 0, stream>>>(Abf, Gbf, out);
}